// Round 2
// baseline (27581.140 us; speedup 1.0000x reference)
//
#include <hip/hip_runtime.h>
#include <hip/hip_bf16.h>
#include <stdint.h>

#define T_SEQ 8192
#define DIMS  2048
#define VOCAB 512
#define GS    ((size_t)VOCAB * DIMS)

typedef unsigned short u16;
typedef unsigned int   uint32;
typedef unsigned long long u64;

__device__ __forceinline__ float lo2f(uint32 u) { return __uint_as_float(u << 16); }
__device__ __forceinline__ float hi2f(uint32 u) { return __uint_as_float(u & 0xffff0000u); }

// DPP row_shr:N add (16-lane row, 0-fill OOB): after N=1,2,4,8 lane 15 (mod 16)
// holds its row's sum. v_add_f32_dpp ~4cy vs ds_bpermute ~30cy.
#define ROW_SHR_ADD(x, N)                                                          \
  x += __int_as_float(__builtin_amdgcn_update_dpp(                                 \
      0, __float_as_int(x), 0x110 + (N), 0xF, 0xF, true))

// ---------------------------------------------------------------- X = Wx.T + bx
__global__ __launch_bounds__(256) void k_build_x(const float* __restrict__ Wx,
                                                 const float* __restrict__ bx,
                                                 float* __restrict__ X) {
  int i = blockIdx.x * 256 + threadIdx.x;      // i = d*VOCAB + v
  int v = i & (VOCAB - 1);
  int d = i >> 9;
  X[(size_t)v * DIMS + d] = Wx[i] + bx[d];
}

// ---------------------------------------------------------------- G_g = X @ Wg.T + bwg
// Output interleaved by gate: G[(v*DIMS + j)*4 + gate].
__global__ __launch_bounds__(256) void k_gate_gemm(const float* __restrict__ X,
                                                   const float* __restrict__ Wg,
                                                   const float* __restrict__ bw,
                                                   float* __restrict__ Gout,
                                                   int gate) {
  __shared__ float Xs[32][64];
  __shared__ float Ws[32][64];
  const int v0 = blockIdx.y * 64;
  const int j0 = blockIdx.x * 64;
  const int tid = threadIdx.x;
  const int tx = tid & 15, ty = tid >> 4;
  float acc[4][4] = {{0.f}};
  for (int k0 = 0; k0 < DIMS; k0 += 32) {
    const int r = tid >> 2, q = tid & 3;
    {
      const float* src = X + (size_t)(v0 + r) * DIMS + k0 + q * 8;
      float4 a = ((const float4*)src)[0];
      float4 b = ((const float4*)src)[1];
      Xs[q*8+0][r]=a.x; Xs[q*8+1][r]=a.y; Xs[q*8+2][r]=a.z; Xs[q*8+3][r]=a.w;
      Xs[q*8+4][r]=b.x; Xs[q*8+5][r]=b.y; Xs[q*8+6][r]=b.z; Xs[q*8+7][r]=b.w;
      const float* wsrc = Wg + (size_t)(j0 + r) * DIMS + k0 + q * 8;
      float4 c = ((const float4*)wsrc)[0];
      float4 e = ((const float4*)wsrc)[1];
      Ws[q*8+0][r]=c.x; Ws[q*8+1][r]=c.y; Ws[q*8+2][r]=c.z; Ws[q*8+3][r]=c.w;
      Ws[q*8+4][r]=e.x; Ws[q*8+5][r]=e.y; Ws[q*8+6][r]=e.z; Ws[q*8+7][r]=e.w;
    }
    __syncthreads();
    #pragma unroll
    for (int k = 0; k < 32; ++k) {
      float xa[4], wb[4];
      *(float4*)xa = *(const float4*)&Xs[k][ty*4];
      *(float4*)wb = *(const float4*)&Ws[k][tx*4];
      #pragma unroll
      for (int a = 0; a < 4; ++a)
        #pragma unroll
        for (int b = 0; b < 4; ++b)
          acc[a][b] = fmaf(xa[a], wb[b], acc[a][b]);
    }
    __syncthreads();
  }
  #pragma unroll
  for (int a = 0; a < 4; ++a)
    #pragma unroll
    for (int b = 0; b < 4; ++b)
      Gout[(((size_t)(v0 + ty*4 + a) * DIMS + j0 + tx*4 + b) << 2) + gate] =
          acc[a][b] + bw[j0 + tx*4 + b];
}

// ---------------------------------------------------------------- recurrence
// Round-5 changes vs round-4:
//  (D) dot restructured: lane L owns float4 indices L+64i (i=0..7) of h for ALL
//      4 gates (weights w4[4][8] = same 128 floats/lane as before). LDS reads
//      drop from 32 b128/lane-step (4x replicated across gate groups) to 8
//      b128/lane-step, wave reads the 8KB h exactly once, fully contiguous.
//      Frees ~580cy/SIMD/step of LDS-pipe issue.
//  (R) reduce via DPP: per gate-acc 4x v_add row_shr:{1,2,4,8} puts row sums in
//      lanes 15/31/47/63, then shfl_xor(16)+shfl_xor(32) -> lane 15 holds ALL
//      four gate totals. No 3-shfl gather; lane 15 runs the 4 independent
//      activation chains (pipelined) and publishes. Tail shortens ~150-250cy,
//      directly ahead of the publish store.
// Protocol (tags, parity double-buffer, selective-retry poll, rotating hs
// writer) unchanged.
template <typename HS> __device__ __forceinline__ void store_h4(HS* hs, size_t idx, float4 v);
template <> __device__ __forceinline__ void store_h4<float>(float* hs, size_t idx, float4 v) {
  *(float4*)(hs + idx) = v;
}
template <> __device__ __forceinline__ void store_h4<u16>(u16* hs, size_t idx, float4 v) {
  __hip_bfloat16 bx = __float2bfloat16(v.x);
  __hip_bfloat16 by = __float2bfloat16(v.y);
  __hip_bfloat16 bz = __float2bfloat16(v.z);
  __hip_bfloat16 bw = __float2bfloat16(v.w);
  ushort4 o;
  o.x = *reinterpret_cast<u16*>(&bx);
  o.y = *reinterpret_cast<u16*>(&by);
  o.z = *reinterpret_cast<u16*>(&bz);
  o.w = *reinterpret_cast<u16*>(&bw);
  *(ushort4*)(hs + idx) = o;
}

template <typename HS>
__global__ __launch_bounds__(512, 2) void k_lstm(
    const int* __restrict__ tokens,
    const float* __restrict__ G,
    uint32* hbuf,
    HS* __restrict__ hs,
    const float* __restrict__ Uf, const float* __restrict__ Ui,
    const float* __restrict__ Uc, const float* __restrict__ Uo,
    const float* __restrict__ bUf, const float* __restrict__ bUi,
    const float* __restrict__ bUc, const float* __restrict__ bUo) {
  __shared__ float4 h4[2][DIMS / 4];
  const int tid  = threadIdx.x;          // 0..511
  const int wave = tid >> 6;             // 0..7
  const int lane = tid & 63;
  const int jr   = blockIdx.x * 8 + wave;

  // (D) weights: lane L covers float4 indices L+64i of row jr, for all 4 gates.
  float4 w4[4][8];
  {
    const float4* r0 = (const float4*)(Uf + (size_t)jr * DIMS);
    const float4* r1 = (const float4*)(Ui + (size_t)jr * DIMS);
    const float4* r2 = (const float4*)(Uc + (size_t)jr * DIMS);
    const float4* r3 = (const float4*)(Uo + (size_t)jr * DIMS);
    #pragma unroll
    for (int i = 0; i < 8; ++i) {
      w4[0][i] = r0[lane + 64 * i];
      w4[1][i] = r1[lane + 64 * i];
      w4[2][i] = r2[lane + 64 * i];
      w4[3][i] = r3[lane + 64 * i];
    }
  }
  #pragma unroll
  for (int g = 0; g < 4; ++g)
    #pragma unroll
    for (int i = 0; i < 8; ++i)
      asm volatile("" : "+v"(w4[g][i].x), "+v"(w4[g][i].y), "+v"(w4[g][i].z), "+v"(w4[g][i].w));

  float creg = 0.f, bF = 0.f, bI = 0.f, bC = 0.f, bO = 0.f;
  float4 gv = make_float4(0.f, 0.f, 0.f, 0.f);
  if (lane == 15) {   // publisher lane (holds all 4 gate totals after reduce)
    bF = bUf[jr]; bI = bUi[jr]; bC = bUc[jr]; bO = bUo[jr];
    gv = ((const float4*)G)[(size_t)tokens[0] * DIMS + jr];
  }
  if (lane == 0) {
    // h0 = 0 with tag 0; buffer-1 tag 0 (!= 1, != poison 0xAA).
    __hip_atomic_store(&hbuf[jr], 0u, __ATOMIC_RELAXED, __HIP_MEMORY_SCOPE_AGENT);
    __hip_atomic_store(&hbuf[DIMS + jr], 0u, __ATOMIC_RELAXED, __HIP_MEMORY_SCOPE_AGENT);
  }

  #pragma unroll 1
  for (int t = 0; t < T_SEQ; ++t) {
    { // stage h_t: thread tid owns h[4*tid..4*tid+3]; poll tags, selective retry
      const u64* hsrc = (const u64*)(hbuf + (size_t)(t & 1) * DIMS) + 2 * tid;
      const uint32 want = (uint32)t & 0xFFu;
      u64 u0 = __hip_atomic_load(hsrc + 0, __ATOMIC_RELAXED, __HIP_MEMORY_SCOPE_AGENT);
      u64 u1 = __hip_atomic_load(hsrc + 1, __ATOMIC_RELAXED, __HIP_MEMORY_SCOPE_AGENT);
      for (;;) {
        const bool ok0 = ((((uint32)u0 ^ want) | ((uint32)(u0 >> 32) ^ want)) & 0xFFu) == 0u;
        const bool ok1 = ((((uint32)u1 ^ want) | ((uint32)(u1 >> 32) ^ want)) & 0xFFu) == 0u;
        if (ok0 && ok1) break;
        if (!ok0) u0 = __hip_atomic_load(hsrc + 0, __ATOMIC_RELAXED, __HIP_MEMORY_SCOPE_AGENT);
        if (!ok1) u1 = __hip_atomic_load(hsrc + 1, __ATOMIC_RELAXED, __HIP_MEMORY_SCOPE_AGENT);
      }
      h4[t & 1][tid] = make_float4(__uint_as_float((uint32)u0),
                                   __uint_as_float((uint32)(u0 >> 32)),
                                   __uint_as_float((uint32)u1),
                                   __uint_as_float((uint32)(u1 >> 32)));
    }
    __syncthreads();
    // rotating coalesced hs writer: one block per step, from staged LDS.
    if ((int)blockIdx.x == (t & 255)) {
      float4 hv4 = h4[t & 1][tid];
      store_h4<HS>(hs, (size_t)t * DIMS + 4 * (size_t)tid, hv4);
    }
    // (D) dot: lane L covers k-chunks L+64i; 8 contiguous b128 reads, 128 fma.
    const float4* hb = h4[t & 1];
    float a0 = 0.f, a1 = 0.f, a2 = 0.f, a3 = 0.f;
    #pragma unroll
    for (int i = 0; i < 8; ++i) {
      float4 hv = hb[lane + 64 * i];
      a0 = fmaf(w4[0][i].x, hv.x, a0); a0 = fmaf(w4[0][i].y, hv.y, a0);
      a0 = fmaf(w4[0][i].z, hv.z, a0); a0 = fmaf(w4[0][i].w, hv.w, a0);
      a1 = fmaf(w4[1][i].x, hv.x, a1); a1 = fmaf(w4[1][i].y, hv.y, a1);
      a1 = fmaf(w4[1][i].z, hv.z, a1); a1 = fmaf(w4[1][i].w, hv.w, a1);
      a2 = fmaf(w4[2][i].x, hv.x, a2); a2 = fmaf(w4[2][i].y, hv.y, a2);
      a2 = fmaf(w4[2][i].z, hv.z, a2); a2 = fmaf(w4[2][i].w, hv.w, a2);
      a3 = fmaf(w4[3][i].x, hv.x, a3); a3 = fmaf(w4[3][i].y, hv.y, a3);
      a3 = fmaf(w4[3][i].z, hv.z, a3); a3 = fmaf(w4[3][i].w, hv.w, a3);
    }
    // (R) reduce: DPP row sums (lanes 15/31/47/63), then xor(16)+xor(32).
    // Lanes 15/31/47/63 end with the true totals; others hold garbage partials.
    ROW_SHR_ADD(a0, 1); ROW_SHR_ADD(a1, 1); ROW_SHR_ADD(a2, 1); ROW_SHR_ADD(a3, 1);
    ROW_SHR_ADD(a0, 2); ROW_SHR_ADD(a1, 2); ROW_SHR_ADD(a2, 2); ROW_SHR_ADD(a3, 2);
    ROW_SHR_ADD(a0, 4); ROW_SHR_ADD(a1, 4); ROW_SHR_ADD(a2, 4); ROW_SHR_ADD(a3, 4);
    ROW_SHR_ADD(a0, 8); ROW_SHR_ADD(a1, 8); ROW_SHR_ADD(a2, 8); ROW_SHR_ADD(a3, 8);
    a0 += __shfl_xor(a0, 16, 64); a1 += __shfl_xor(a1, 16, 64);
    a2 += __shfl_xor(a2, 16, 64); a3 += __shfl_xor(a3, 16, 64);
    a0 += __shfl_xor(a0, 32, 64); a1 += __shfl_xor(a1, 32, 64);
    a2 += __shfl_xor(a2, 32, 64); a3 += __shfl_xor(a3, 32, 64);
    if (lane == 15) {
      const float yf = a0 + bF + gv.x;
      const float yi = a1 + bI + gv.y;
      const float yc = a2 + bC + gv.z;
      const float yo = a3 + bO + gv.w;
      const float fg = 1.f / (1.f + __expf(-yf));
      const float ig = 1.f / (1.f + __expf(-yi));
      const float cn = 1.f - 2.f / (1.f + __expf(2.f * yc));
      const float og = 1.f / (1.f + __expf(-yo));
      creg = fg * creg + ig * cn;
      const float th = 1.f - 2.f / (1.f + __expf(2.f * creg));
      const float hv = og * th;
      const uint32 tb = (__float_as_uint(hv) & 0xFFFFFF00u) | ((uint32)(t + 1) & 0xFFu);
      __hip_atomic_store(&hbuf[(size_t)((t + 1) & 1) * DIMS + jr], tb,
                         __ATOMIC_RELAXED, __HIP_MEMORY_SCOPE_AGENT);
      const int tn = (t + 1 < T_SEQ) ? t + 1 : T_SEQ - 1;
      gv = ((const float4*)G)[(size_t)tokens[tn] * DIMS + jr];  // prefetch t+1
    }
  }
}

// ---------------------------------------------------------------- logits = hs @ V.T + bv
template <typename HS> __device__ __forceinline__ void load8(const HS* p, float* o);
template <> __device__ __forceinline__ void load8<float>(const float* p, float* o) {
  float4 a = ((const float4*)p)[0], b = ((const float4*)p)[1];
  o[0]=a.x; o[1]=a.y; o[2]=a.z; o[3]=a.w; o[4]=b.x; o[5]=b.y; o[6]=b.z; o[7]=b.w;
}
template <> __device__ __forceinline__ void load8<u16>(const u16* p, float* o) {
  uint4 u = *(const uint4*)p;
  o[0]=lo2f(u.x); o[1]=hi2f(u.x); o[2]=lo2f(u.y); o[3]=hi2f(u.y);
  o[4]=lo2f(u.z); o[5]=hi2f(u.z); o[6]=lo2f(u.w); o[7]=hi2f(u.w);
}

template <typename HS>
__global__ __launch_bounds__(256) void k_out_gemm(const HS* __restrict__ hs,
                                                  const float* __restrict__ V,
                                                  const float* __restrict__ bvb,
                                                  float* __restrict__ logits) {
  __shared__ float As[32][64];
  __shared__ float Bs[32][128];
  const int t0 = blockIdx.x * 64;
  const int v0 = blockIdx.y * 128;
  const int tid = threadIdx.x;
  const int tx = tid & 15, ty = tid >> 4;
  float acc[4][8] = {{0.f}};
  for (int k0 = 0; k0 < DIMS; k0 += 32) {
    {
      const int r = tid >> 2, q = tid & 3;
      float o8[8];
      load8<HS>(hs + (size_t)(t0 + r) * DIMS + k0 + q * 8, o8);
      #pragma unroll
      for (int s = 0; s < 8; ++s) As[q*8+s][r] = o8[s];
      const int rb = tid >> 1, c0 = (tid & 1) * 2;
      #pragma unroll
      for (int c = 0; c < 2; ++c) {
        float p8[8];
        load8<float>(V + (size_t)(v0 + rb) * DIMS + k0 + (c0 + c) * 8, p8);
        #pragma unroll
        for (int s = 0; s < 8; ++s) Bs[(c0+c)*8+s][rb] = p8[s];
      }
    }
    __syncthreads();
    #pragma unroll
    for (int k = 0; k < 32; ++k) {
      float av[4], bw8[8];
      *(float4*)av = *(const float4*)&As[k][ty*4];
      *(float4*)&bw8[0] = *(const float4*)&Bs[k][tx*8];
      *(float4*)&bw8[4] = *(const float4*)&Bs[k][tx*8+4];
      #pragma unroll
      for (int a = 0; a < 4; ++a)
        #pragma unroll
        for (int b = 0; b < 8; ++b)
          acc[a][b] = fmaf(av[a], bw8[b], acc[a][b]);
    }
    __syncthreads();
  }
  #pragma unroll
  for (int a = 0; a < 4; ++a)
    #pragma unroll
    for (int b = 0; b < 8; ++b)
      logits[(size_t)(t0 + ty*4 + a) * VOCAB + v0 + tx*8 + b] =
          acc[a][b] + bvb[v0 + tx*8 + b];
}

// ---------------------------------------------------------------- log_softmax rows (in-place)
__global__ __launch_bounds__(256) void k_logsoftmax(float* __restrict__ logits) {
  const int t = blockIdx.x;
  const int tid = threadIdx.x;
  float* row = logits + (size_t)t * VOCAB;
  float x0 = row[tid], x1 = row[tid + 256];
  float m = fmaxf(x0, x1);
  #pragma unroll
  for (int d = 32; d; d >>= 1) m = fmaxf(m, __shfl_xor(m, d, 64));
  __shared__ float r1[4], r2[4];
  if ((tid & 63) == 0) r1[tid >> 6] = m;
  __syncthreads();
  m = fmaxf(fmaxf(r1[0], r1[1]), fmaxf(r1[2], r1[3]));
  float s = __expf(x0 - m) + __expf(x1 - m);
  #pragma unroll
  for (int d = 32; d; d >>= 1) s += __shfl_xor(s, d, 64);
  if ((tid & 63) == 0) r2[tid >> 6] = s;
  __syncthreads();
  s = r2[0] + r2[1] + r2[2] + r2[3];
  const float lse = m + __logf(s);
  row[tid] = x0 - lse;
  row[tid + 256] = x1 - lse;
}

// ----------------------------------------------------------------
extern "C" void kernel_launch(void* const* d_in, const int* in_sizes, int n_in,
                              void* d_out, int out_size, void* d_ws, size_t ws_size,
                              hipStream_t stream) {
  const int*   tokens = (const int*)d_in[0];
  const float* Wx  = (const float*)d_in[1];
  const float* bx  = (const float*)d_in[2];
  const float* Uf  = (const float*)d_in[3];
  const float* bUf = (const float*)d_in[4];
  const float* Wf  = (const float*)d_in[5];
  const float* bwf = (const float*)d_in[6];
  const float* Ui  = (const float*)d_in[7];
  const float* bUi = (const float*)d_in[8];
  const float* Wi  = (const float*)d_in[9];
  const float* bwi = (const float*)d_in[10];
  const float* Uc  = (const float*)d_in[11];
  const float* bUc = (const float*)d_in[12];
  const float* Wc  = (const float*)d_in[13];
  const float* bwc = (const float*)d_in[14];
  const float* Uo  = (const float*)d_in[15];
  const float* bUo = (const float*)d_in[16];
  const float* Wo  = (const float*)d_in[17];
  const float* bwo = (const float*)d_in[18];
  const float* V   = (const float*)d_in[19];
  const float* bv  = (const float*)d_in[20];

  char* ws = (char*)d_ws;
  float* X = (float*)ws;                                   // 4 MiB
  float* G = (float*)(ws + 4194304ull);                    // 16 MiB (gate-interleaved)
  uint32* hbuf = (uint32*)(ws + 20971520ull);              // 16 KiB (32 reserved)
  char* rest = ws + 21004288ull;
  const bool f32path = ws_size >= 88113152ull;             // + hs f32 (64 MiB)

  k_build_x<<<dim3((DIMS * VOCAB) / 256), dim3(256), 0, stream>>>(Wx, bx, X);
  dim3 gg(DIMS / 64, VOCAB / 64);
  k_gate_gemm<<<gg, dim3(256), 0, stream>>>(X, Wf, bwf, G, 0);
  k_gate_gemm<<<gg, dim3(256), 0, stream>>>(X, Wi, bwi, G, 1);
  k_gate_gemm<<<gg, dim3(256), 0, stream>>>(X, Wc, bwc, G, 2);
  k_gate_gemm<<<gg, dim3(256), 0, stream>>>(X, Wo, bwo, G, 3);

  float* logits = (float*)d_out;   // logits built in d_out, log_softmax in-place
  if (f32path) {
    float* hs = (float*)rest;
    k_lstm<float><<<dim3(256), dim3(512), 0, stream>>>(
        tokens, G, hbuf, hs, Uf, Ui, Uc, Uo, bUf, bUi, bUc, bUo);
    k_out_gemm<float><<<dim3(T_SEQ / 64, VOCAB / 128), dim3(256), 0, stream>>>(
        hs, V, bv, logits);
  } else {
    u16* hs = (u16*)rest;
    k_lstm<u16><<<dim3(256), dim3(512), 0, stream>>>(
        tokens, G, hbuf, hs, Uf, Ui, Uc, Uo, bUf, bUi, bUc, bUo);
    k_out_gemm<u16><<<dim3(T_SEQ / 64, VOCAB / 128), dim3(256), 0, stream>>>(
        hs, V, bv, logits);
  }
  k_logsoftmax<<<dim3(T_SEQ), dim3(256), 0, stream>>>(logits);
}